// Round 12
// baseline (183.805 us; speedup 1.0000x reference)
//
#include <hip/hip_runtime.h>

#define NPTS 8192      // H*W
#define BCLS 4         // C
#define NP   6         // B*(C-1) pairs
#define R2   9.0f
#define RAD  3.0f
#define GRD  128       // fine grid — cell = max(6, span/127) ~= 2*RAD
#define NCELL (GRD*GRD)
#define CAP  4096      // per-pair compact-point capacity (M ~ 2048 +- 40)
#define KBLK 64        // front kernel blocks
#define KTHR 256       // front kernel threads (KBLK*KTHR == B*NPTS)
#define NSL  8         // slices per pair for wide kernels
#define WBLK (NP*NSL)  // 48 wide blocks
#define WTHR 256

#define ST_U 0u
#define ST_A 1u
#define ST_D 2u

// ---------------------------------------------------------------------------
// R25: REPLACE the NMS fixpoint with an exact sequential-equivalent.
// R24 post-mortem: wave-interleave null (+ bank conflicts 40k->71k from the
// strided LDS pattern) — chains don't collapse across concurrently-executing
// waves. Refutation set now complete: barriers(R16), rescans(R14/R22), scan
// volume(R20), blocker lists(R15), ordering(R24). So: don't run a fixpoint.
// Pixel indices are spatially RANDOM => 64 consecutive ni-order points are
// spatially scattered (intra-chunk in-radius pairs ~2.5/chunk). New engine:
//  1. slist = points sorted by ni (presence bitmask + prefix; parallel).
//  2. Wave 0 processes chunks of 64 in ni order: ONE window scan per point
//     EVER (earlier chunks final; U-cands with nf<ni are provably in-chunk ->
//     64-bit lane mask via chunkLane map); intra-chunk = ballot loop
//     (progress: lowest undecided lane's nbr ⊆ decided lower lanes).
// Zero barriers, zero pending lists, M total scans. Same _rn arithmetic,
// strict <, same suppression semantics => bit-identical to sequential greedy.
// k_front/k_assign/k_out unchanged from R23.
// ---------------------------------------------------------------------------

__global__ __launch_bounds__(KTHR) void k_front(
    const float* __restrict__ seg, const float* __restrict__ lidar,
    float* __restrict__ xs, float* __restrict__ ys,
    unsigned int* __restrict__ ns, unsigned int* __restrict__ counts,
    float* __restrict__ ksum, float* __restrict__ out)
{
    const int tid = threadIdx.x, lane = tid & 63;
    const int idx = blockIdx.x * KTHR + tid;       // [0, B*NPTS)
    const int b = idx >> 13, n = idx & 8191;

    __shared__ float ex[KTHR], ey[KTHR];
    __shared__ unsigned short en[KTHR];
    __shared__ unsigned int cnt6[6], off6[6], pos6[6];

    if (tid < 6) cnt6[tid] = 0;
    __syncthreads();

    // per-pixel argmax (strict >: first index wins ties)
    const float* segb = seg + (size_t)b * BCLS * NPTS + n;
    float bv = segb[0];
    int bc = 0;
    #pragma unroll
    for (int c = 1; c < BCLS; ++c) {
        float v = segb[(size_t)c * NPTS];
        if (v > bv) { bv = v; bc = c; }
    }
    const float x = lidar[(size_t)b * 2 * NPTS + n];
    const float y = lidar[(size_t)b * 2 * NPTS + NPTS + n];
    const int p = (bc > 0) ? (b * 3 + bc - 1) : -1;

    // phase A: wave-aggregated per-pair counts
    #pragma unroll
    for (int q = 0; q < 6; ++q) {
        unsigned long long bal = __ballot(p == q);
        if (lane == 0 && bal) atomicAdd(&cnt6[q], (unsigned int)__popcll(bal));
    }
    __syncthreads();
    if (tid == 0) {
        unsigned int a = 0;
        #pragma unroll
        for (int q = 0; q < 6; ++q) { off6[q] = a; pos6[q] = a; a += cnt6[q]; }
    }
    __syncthreads();
    // phase B: wave-aggregated placement into pair-grouped staging
    #pragma unroll
    for (int q = 0; q < 6; ++q) {
        unsigned long long bal = __ballot(p == q);
        if (bal) {
            int ldr = __builtin_ctzll(bal);
            unsigned int wb = 0;
            if (lane == ldr) wb = atomicAdd(&pos6[q], (unsigned int)__popcll(bal));
            wb = __shfl(wb, ldr, 64);
            if (p == q) {
                unsigned int s = wb + (unsigned int)__popcll(bal & ((1ull << lane) - 1ull));
                ex[s] = x; ey[s] = y; en[s] = (unsigned short)n;
            }
        }
    }
    __syncthreads();
    // flush grouped staging to this block's slab chunk + counts row
    {
        const unsigned int total = off6[5] + cnt6[5];
        const int gbase = blockIdx.x * KTHR;
        for (int k = tid; k < (int)total; k += KTHR) {
            xs[gbase + k] = ex[k];
            ys[gbase + k] = ey[k];
            ns[gbase + k] = (unsigned int)en[k];
        }
        if (tid < 6) counts[blockIdx.x * 6 + tid] = cnt6[tid];
    }
    // zero out+ok (36864 float4) and ksum = ksx|ksy|kcn (73728 f = 18432 f4)
    {
        float4* o4 = (float4*)out;
        for (int k = idx; k < 36864; k += KBLK * KTHR)
            o4[k] = make_float4(0.f, 0.f, 0.f, 0.f);
        float4* s4 = (float4*)ksum;
        for (int k = idx; k < 18432; k += KBLK * KTHR)
            s4[k] = make_float4(0.f, 0.f, 0.f, 0.f);
    }
}

// ---------------------------------------------------------------------------
__global__ __launch_bounds__(1024) void k_mid(
    const float* __restrict__ xs, const float* __restrict__ ys,
    const unsigned int* __restrict__ ns, const unsigned int* __restrict__ counts,
    float2* __restrict__ sps_g, unsigned int* __restrict__ cmb_g,
    unsigned int* __restrict__ cellpack_g, float* __restrict__ bbox_g,
    int* __restrict__ M_g,
    unsigned long long* __restrict__ ballots_g, unsigned int* __restrict__ base_g)
{
    const int p = blockIdx.x;
    const int tid = threadIdx.x, lane = tid & 63, wv = tid >> 6;

    __shared__ float2 sps[CAP];                 // 32 KB
    __shared__ unsigned int cmb[CAP];           // 16 KB
    __shared__ unsigned int cellpack[NCELL];    // 64 KB
    __shared__ unsigned short idxOf[NPTS];      // 16 KB: pixel -> grid idx
    __shared__ unsigned short slist[CAP];       //  8 KB: ni-sorted grid idxs
    __shared__ unsigned char chunkLane[CAP];    //  4 KB: grid idx -> chunk lane
    __shared__ unsigned long long pb[128];      //  1 KB: pixel presence bits
    __shared__ unsigned int woff[128];
    __shared__ unsigned long long ballots[64];
    __shared__ unsigned int base64[64];
    __shared__ unsigned int wtot[16];
    __shared__ float redbuf[4][16];
    __shared__ unsigned int csrc[KBLK], cdst[KBLK];
    __shared__ float sbminx, sbminy, scell;
    __shared__ int sM;

    for (int k = tid; k < CAP; k += 1024) cmb[k] = ST_U;
    for (int k = tid; k < NCELL; k += 1024) cellpack[k] = 0u;
    if (tid < 128) pb[tid] = 0ull;

    // ---- chunk table: lane k of wave 0 owns source block k ----
    if (wv == 0) {
        unsigned int c6[6];
        #pragma unroll
        for (int q = 0; q < 6; ++q) c6[q] = counts[lane * 6 + q];
        unsigned int within = 0;
        for (int q = 0; q < p; ++q) within += c6[q];
        unsigned int len = c6[p];
        unsigned int v = len;
        for (int d = 1; d < 64; d <<= 1) {
            unsigned int u = __shfl_up(v, d, 64);
            if (lane >= d) v += u;
        }
        csrc[lane] = lane * KTHR + within;
        cdst[lane] = v - len;
        if (lane == 63) sM = (int)(v < CAP ? v : CAP);
    }
    __syncthreads();
    const int M = sM;

    // ---- gather compact entries into regs + bbox ----
    float xq[4], yq[4];
    unsigned int nq[4];
    int liq[4];
    {
        float mnx = 3e38f, mxx = -3e38f, mny = 3e38f, mxy = -3e38f;
        #pragma unroll
        for (int q = 0; q < 4; ++q) {
            int li = q * 1024 + tid;
            liq[q] = li;
            if (li < M) {
                int lo = 0, hi = KBLK - 1;          // last k with cdst[k] <= li
                #pragma unroll
                for (int s = 0; s < 6; ++s) {
                    int mid = (lo + hi + 1) >> 1;
                    if (cdst[mid] <= (unsigned int)li) lo = mid; else hi = mid - 1;
                }
                int si = csrc[lo] + (li - cdst[lo]);
                float x = xs[si], y = ys[si];
                xq[q] = x; yq[q] = y; nq[q] = ns[si];
                mnx = fminf(mnx, x); mxx = fmaxf(mxx, x);
                mny = fminf(mny, y); mxy = fmaxf(mxy, y);
            }
        }
        for (int d = 32; d; d >>= 1) {
            mnx = fminf(mnx, __shfl_xor(mnx, d, 64));
            mxx = fmaxf(mxx, __shfl_xor(mxx, d, 64));
            mny = fminf(mny, __shfl_xor(mny, d, 64));
            mxy = fmaxf(mxy, __shfl_xor(mxy, d, 64));
        }
        if (lane == 0) { redbuf[0][wv] = mnx; redbuf[1][wv] = mxx;
                         redbuf[2][wv] = mny; redbuf[3][wv] = mxy; }
    }
    __syncthreads();
    if (tid == 0) {
        float a = redbuf[0][0], b2 = redbuf[1][0], c = redbuf[2][0], d = redbuf[3][0];
        for (int q = 1; q < 16; ++q) {
            a = fminf(a, redbuf[0][q]); b2 = fmaxf(b2, redbuf[1][q]);
            c = fminf(c, redbuf[2][q]); d = fmaxf(d, redbuf[3][q]);
        }
        sbminx = a; sbminy = c;
        scell = fmaxf(2.0f * RAD, fmaxf(b2 - a, d - c) / 127.0f);  // cell >= 2*RAD
    }
    __syncthreads();
    const float bminx = sbminx, bminy = sbminy, inv = 1.0f / scell;

    // ---- grid count / scan / scatter (coords held in regs) ----
    int cellq[4];
    #pragma unroll
    for (int q = 0; q < 4; ++q) {
        if (liq[q] < M) {
            int ix = min(GRD - 1, max(0, (int)((xq[q] - bminx) * inv)));
            int iy = min(GRD - 1, max(0, (int)((yq[q] - bminy) * inv)));
            cellq[q] = iy * GRD + ix;
            atomicAdd(&cellpack[cellq[q]], 1u);
        } else cellq[q] = -1;
    }
    __syncthreads();
    {
        unsigned int c16[16], t16 = 0;          // thread owns 16 cells
        #pragma unroll
        for (int q = 0; q < 16; ++q) { c16[q] = cellpack[tid * 16 + q]; t16 += c16[q]; }
        unsigned int v = t16;
        for (int d = 1; d < 64; d <<= 1) {
            unsigned int u = __shfl_up(v, d, 64);
            if (lane >= d) v += u;
        }
        if (lane == 63) wtot[wv] = v;
        __syncthreads();
        if (tid == 0) {
            unsigned int acc = 0;
            for (int q = 0; q < 16; ++q) { unsigned int t = wtot[q]; wtot[q] = acc; acc += t; }
        }
        __syncthreads();
        unsigned int excl = wtot[wv] + v - t16;
        #pragma unroll
        for (int q = 0; q < 16; ++q) { cellpack[tid * 16 + q] = excl << 16; excl += c16[q]; }
    }
    __syncthreads();
    #pragma unroll
    for (int q = 0; q < 4; ++q) {
        if (cellq[q] >= 0) {
            unsigned int old = atomicAdd(&cellpack[cellq[q]], 1u);
            unsigned int pos = (old >> 16) + (old & 0xffffu);
            sps[pos] = make_float2(xq[q], yq[q]);
            cmb[pos] = (nq[q] << 2) | ST_U;
        }
    }   // cellpack now = start<<16 | cnt; sps/cmb grid-space
    __syncthreads();

    // ---- pixel->grid map + presence bits; dump build state ----
    for (int e = tid; e < M; e += 1024) {
        unsigned int n = cmb[e] >> 2;
        idxOf[n] = (unsigned short)e;
        atomicOr(&pb[n >> 6], 1ull << (n & 63));
    }
    const int pb_ = p * CAP;
    for (int k = tid; k < CAP; k += 1024) sps_g[pb_ + k] = sps[k];
    for (int k = tid; k < NCELL; k += 1024) cellpack_g[p * NCELL + k] = cellpack[k];
    if (tid == 0) {
        bbox_g[p * 4 + 0] = bminx; bbox_g[p * 4 + 1] = bminy;
        bbox_g[p * 4 + 2] = inv;
        M_g[p] = M;
    }
    __syncthreads();

    // ---- slist: ni-sorted grid indices via word-popcount prefix ----
    if (wv == 0) {
        unsigned int c0 = (unsigned int)__popcll(pb[2 * lane]);
        unsigned int c1 = (unsigned int)__popcll(pb[2 * lane + 1]);
        unsigned int s = c0 + c1, v = s;
        for (int d = 1; d < 64; d <<= 1) {
            unsigned int u = __shfl_up(v, d, 64);
            if (lane >= d) v += u;
        }
        woff[2 * lane] = v - s;
        woff[2 * lane + 1] = v - c1;
    }
    __syncthreads();
    if (tid < 128) {
        unsigned long long w = pb[tid];
        unsigned int o = woff[tid];
        while (w) {
            int b = __builtin_ctzll(w);
            w &= w - 1;
            slist[o++] = idxOf[(tid << 6) + b];
        }
    }
    __syncthreads();

    // ---- serial-chunk NMS on wave 0: exact sequential greedy ----
    #define SER_ROW(CY, CX0, CX1, NI, ME, EXTD, NBR)                              \
    {                                                                             \
        unsigned int wa = cellpack[(CY) * GRD + (CX0)];                           \
        unsigned int wb = cellpack[(CY) * GRD + (CX1)];                           \
        unsigned int f0 = wa >> 16, f1 = (wb >> 16) + (wb & 0xffffu);             \
        for (unsigned int f = f0; f < f1; ++f) {                                  \
            unsigned int wf = cmb[f];                                             \
            float2 q = sps[f];                                                    \
            float dx = __fsub_rn((ME).x, q.x), dy = __fsub_rn((ME).y, q.y);       \
            float d2 = __fadd_rn(__fmul_rn(dx, dx), __fmul_rn(dy, dy));           \
            bool in = (d2 < R2) & ((int)(wf >> 2) < (NI));                        \
            unsigned int st = wf & 3u;                                            \
            EXTD |= in & (st == ST_A);                                            \
            if (in & (st == ST_U)) NBR |= 1ull << chunkLane[f];                   \
        }                                                                         \
    }
    if (wv == 0) {
        const int nch = (M + 63) >> 6;
        for (int c = 0; c < nch; ++c) {
            int i = (c << 6) + lane;
            bool act = i < M;
            int e = act ? (int)slist[i] : 0;
            unsigned int w = cmb[e];
            int ni = (int)(w >> 2);
            float2 me = sps[e];
            if (act) chunkLane[e] = (unsigned char)lane;   // 1 instr: all lanes
            bool extdead = false;                          // write before any read
            unsigned long long nbr = 0ull;
            if (act) {
                int cx0 = max(0, (int)((me.x - RAD - bminx) * inv));
                int cx1 = min(GRD - 1, (int)((me.x + RAD - bminx) * inv));
                int cy0 = max(0, (int)((me.y - RAD - bminy) * inv));
                int cy1 = min(GRD - 1, (int)((me.y + RAD - bminy) * inv));
                SER_ROW(cy0, cx0, cx1, ni, me, extdead, nbr);
                if (cy1 > cy0) SER_ROW(cy1, cx0, cx1, ni, me, extdead, nbr);
            }
            // intra-chunk resolve: nbr ⊆ lower lanes (slist ni-sorted) =>
            // lowest undecided lane decides each iteration
            bool decided = !act, kept = false;
            unsigned long long decidedM = __ballot(decided);
            unsigned long long keptM = 0ull;
            while (decidedM != ~0ull) {
                bool dienow = !decided && (extdead || ((nbr & keptM) != 0ull));
                bool keepnow = !decided && !dienow && ((nbr & ~decidedM) == 0ull);
                unsigned long long dM = __ballot(dienow);
                unsigned long long kM = __ballot(keepnow);
                keptM |= kM;
                decidedM |= dM | kM;
                decided = decided || dienow || keepnow;
                kept = kept || keepnow;
            }
            if (act) cmb[e] = (w & ~3u) | (kept ? ST_A : ST_D);
        }
    }
    __syncthreads();

    // ---- kept-rank: ballot bitmask + wave-scanned prefix; dump cmb + rank ----
    for (int k = 0; k < 4; ++k) {
        int e = (k << 10) + tid;
        unsigned long long bal = __ballot((cmb[e] & 3u) == ST_A);  // e>=M stays U
        if (lane == 0) ballots[(k << 4) + wv] = bal;
    }
    __syncthreads();
    if (wv == 0) {
        unsigned int s = (unsigned int)__popcll(ballots[lane]);
        unsigned int v = s;
        for (int d = 1; d < 64; d <<= 1) {
            unsigned int u = __shfl_up(v, d, 64);
            if (lane >= d) v += u;
        }
        base64[lane] = v - s;
    }
    __syncthreads();
    for (int k = tid; k < CAP; k += 1024) cmb_g[pb_ + k] = cmb[k];
    if (tid < 64) { ballots_g[(p << 6) + tid] = ballots[tid]; base_g[(p << 6) + tid] = base64[tid]; }
}

#define KRANK_G(P, E) ((int)base_g[((P) << 6) + ((E) >> 6)] +                     \
    __popcll(ballots_g[((P) << 6) + ((E) >> 6)] & ((1ull << ((E) & 63)) - 1ull)))

// ---------------------------------------------------------------------------
__global__ __launch_bounds__(WTHR) void k_assign(
    const float2* __restrict__ sps_g, const unsigned int* __restrict__ cmb_g,
    const unsigned int* __restrict__ cellpack_g, const float* __restrict__ bbox_g,
    const int* __restrict__ M_g,
    const unsigned long long* __restrict__ ballots_g, const unsigned int* __restrict__ base_g,
    float* __restrict__ ksx, float* __restrict__ ksy, float* __restrict__ kcn)
{
    const int p = blockIdx.x / NSL, s = blockIdx.x % NSL;
    const int tid = threadIdx.x;
    const int M = M_g[p];
    const float bminx = bbox_g[p * 4], bminy = bbox_g[p * 4 + 1], inv = bbox_g[p * 4 + 2];
    const float2* sp = sps_g + p * CAP;
    const unsigned int* cm = cmb_g + p * CAP;
    const unsigned int* cp = cellpack_g + p * NCELL;

    const int chunk = (M + NSL - 1) / NSL;
    const int e0 = s * chunk, e1 = min(M, e0 + chunk);

    #define G_ROW_ARGMIN(CY, CX0, CX1, ME, BD, BE, BN)                            \
    {                                                                             \
        unsigned int wa = cp[(CY) * GRD + (CX0)];                                 \
        unsigned int wb = cp[(CY) * GRD + (CX1)];                                 \
        unsigned int f0 = wa >> 16, f1 = (wb >> 16) + (wb & 0xffffu);             \
        for (unsigned int f = f0; f < f1; ++f) {                                  \
            unsigned int wf = cm[f];                                              \
            float2 q = sp[f];                                                     \
            float dx = __fsub_rn((ME).x, q.x), dy = __fsub_rn((ME).y, q.y);       \
            float d2 = __fadd_rn(__fmul_rn(dx, dx), __fmul_rn(dy, dy));           \
            int nf = (int)(wf >> 2);                                              \
            bool better = ((wf & 3u) == ST_A) &                                   \
                          ((d2 < BD) | ((d2 == BD) & (nf < BN)));                 \
            BD = better ? d2 : BD;                                                \
            BE = better ? (int)f : BE;                                            \
            BN = better ? nf : BN;                                                \
        }                                                                         \
    }
    for (int e = e0 + tid; e < e1; e += WTHR) {
        unsigned int w = cm[e];
        float2 me = sp[e];
        int be;
        if ((w & 3u) == ST_A) {
            be = e;                              // self: unique d2 = 0
        } else {
            int cx0 = max(0, (int)((me.x - RAD - bminx) * inv));
            int cx1 = min(GRD - 1, (int)((me.x + RAD - bminx) * inv));
            int cy0 = max(0, (int)((me.y - RAD - bminy) * inv));
            int cy1 = min(GRD - 1, (int)((me.y + RAD - bminy) * inv));
            float bd = 3e38f;
            be = -1;
            int bn = 1 << 30;
            G_ROW_ARGMIN(cy0, cx0, cx1, me, bd, be, bn);
            if (cy1 > cy0) G_ROW_ARGMIN(cy1, cx0, cx1, me, bd, be, bn);
            if (be < 0) continue;
        }
        int r = KRANK_G(p, be);
        atomicAdd(&ksx[p * CAP + r], me.x);
        atomicAdd(&ksy[p * CAP + r], me.y);
        atomicAdd(&kcn[p * CAP + r], 1.0f);
    }
}

// ---------------------------------------------------------------------------
__global__ __launch_bounds__(WTHR) void k_out(
    const unsigned int* __restrict__ cmb_g, const int* __restrict__ M_g,
    const unsigned long long* __restrict__ ballots_g, const unsigned int* __restrict__ base_g,
    const float* __restrict__ ksx, const float* __restrict__ ksy,
    const float* __restrict__ kcn, float* __restrict__ out)
{
    const int p = blockIdx.x / NSL, s = blockIdx.x % NSL;
    const int tid = threadIdx.x;
    const int M = M_g[p];
    const unsigned int* cm = cmb_g + p * CAP;
    const int base = p * NPTS;
    float* ok = out + (size_t)2 * NP * NPTS + base;

    const int chunk = (M + NSL - 1) / NSL;
    const int e0 = s * chunk, e1 = min(M, e0 + chunk);

    for (int e = e0 + tid; e < e1; e += WTHR) {
        unsigned int w = cm[e];
        if ((w & 3u) != ST_A) continue;
        int n = (int)(w >> 2);
        int r = KRANK_G(p, e);
        float c = kcn[p * CAP + r];
        out[2 * (base + n)]     = ksx[p * CAP + r] / c;   // c >= 1 (self-assign)
        out[2 * (base + n) + 1] = ksy[p * CAP + r] / c;
        ok[n] = 1.0f;
    }
}

// ---------------------------------------------------------------------------
extern "C" void kernel_launch(void* const* d_in, const int* in_sizes, int n_in,
                              void* d_out, int out_size, void* d_ws, size_t ws_size,
                              hipStream_t stream) {
    const float* seg   = (const float*)d_in[0];   // [B,C,H,W] f32
    const float* lidar = (const float*)d_in[1];   // [B,2,H,W] f32
    float* out = (float*)d_out;
    float* wsf = (float*)d_ws;

    float* xs = wsf;                                          // 16384
    float* ys = wsf + 16384;                                  // 16384
    unsigned int* ns = (unsigned int*)(wsf + 32768);          // 16384
    unsigned int* counts = (unsigned int*)(wsf + 49152);      // 384
    float2* sps_g = (float2*)(wsf + 49536);                   // 6*4096 f2 -> 98688
    unsigned int* cmb_g = (unsigned int*)(wsf + 98688);       // 24576    -> 123264
    unsigned int* cellpack_g = (unsigned int*)(wsf + 123264); // 98304    -> 221568
    float* bbox_g = wsf + 221568;                             // 24
    int* M_g = (int*)(wsf + 221592);                          // 6 (+2 pad)
    unsigned long long* ballots_g = (unsigned long long*)(wsf + 221600); // 384 u64
    unsigned int* base_g = (unsigned int*)(wsf + 222368);     // 384
    float* ksx = wsf + 222752;                                // 24576
    float* ksy = wsf + 247328;                                // 24576
    float* kcn = wsf + 271904;                                // 24576

    k_front <<<KBLK, KTHR, 0, stream>>>(seg, lidar, xs, ys, ns, counts, ksx, out);
    k_mid   <<<NP, 1024, 0, stream>>>(xs, ys, ns, counts, sps_g, cmb_g, cellpack_g,
                                      bbox_g, M_g, ballots_g, base_g);
    k_assign<<<WBLK, WTHR, 0, stream>>>(sps_g, cmb_g, cellpack_g, bbox_g, M_g,
                                        ballots_g, base_g, ksx, ksy, kcn);
    k_out   <<<WBLK, WTHR, 0, stream>>>(cmb_g, M_g, ballots_g, base_g, ksx, ksy, kcn, out);
}

// Round 13
// 133.688 us; speedup vs baseline: 1.3749x; 1.3749x over previous
//
#include <hip/hip_runtime.h>

#define NPTS 8192      // H*W
#define BCLS 4         // C
#define NP   6         // B*(C-1) pairs
#define R2   9.0f
#define RAD  3.0f
#define GRD  128       // fine grid — cell = max(6, span/127) ~= 2*RAD
#define NCELL (GRD*GRD)
#define CAP  4096      // per-pair compact-point capacity (M ~ 2048 +- 40)
#define KBLK 64        // front kernel blocks
#define KTHR 256       // front kernel threads (KBLK*KTHR == B*NPTS)
#define NSL  8         // slices per pair for wide kernels
#define WBLK (NP*NSL)  // 48 wide blocks
#define WTHR 256

#define ST_U 0u
#define ST_A 1u
#define ST_D 2u

// ---------------------------------------------------------------------------
// R26: hybrid NMS = parallel round-0 + chunk-serial PENDING resolution.
// R25 post-mortem: chunk-serial is EXACT (absmax 0) but 32 full-M chunks on
// one wave = latency death (~3.3us/chunk, zero TLP). Hybrid: R23's 16-wave
// round-0 resolves ~65% (~3us); only pending (~700) goes chunk-serial
// (~11 chunks), with 8-wide batched LDS loads (safe: serial flags are pure
// OR-accumulation, order-independent; batching is correct medicine in the
// single-wave latency-bound regime, unlike R17's TLP-rich regime).
// Same-chunk lane = rank via pixel-bitmask popcount (pb/woff) — no lists,
// no caps, no overflow paths. Exactness: single-wave program order finalizes
// earlier chunks before later scans; U & nf<ni => same chunk; ballot resolve
// is R25's field-verified loop. k_front/k_assign/k_out verbatim R23.
// ---------------------------------------------------------------------------

__global__ __launch_bounds__(KTHR) void k_front(
    const float* __restrict__ seg, const float* __restrict__ lidar,
    float* __restrict__ xs, float* __restrict__ ys,
    unsigned int* __restrict__ ns, unsigned int* __restrict__ counts,
    float* __restrict__ ksum, float* __restrict__ out)
{
    const int tid = threadIdx.x, lane = tid & 63;
    const int idx = blockIdx.x * KTHR + tid;       // [0, B*NPTS)
    const int b = idx >> 13, n = idx & 8191;

    __shared__ float ex[KTHR], ey[KTHR];
    __shared__ unsigned short en[KTHR];
    __shared__ unsigned int cnt6[6], off6[6], pos6[6];

    if (tid < 6) cnt6[tid] = 0;
    __syncthreads();

    // per-pixel argmax (strict >: first index wins ties)
    const float* segb = seg + (size_t)b * BCLS * NPTS + n;
    float bv = segb[0];
    int bc = 0;
    #pragma unroll
    for (int c = 1; c < BCLS; ++c) {
        float v = segb[(size_t)c * NPTS];
        if (v > bv) { bv = v; bc = c; }
    }
    const float x = lidar[(size_t)b * 2 * NPTS + n];
    const float y = lidar[(size_t)b * 2 * NPTS + NPTS + n];
    const int p = (bc > 0) ? (b * 3 + bc - 1) : -1;

    // phase A: wave-aggregated per-pair counts
    #pragma unroll
    for (int q = 0; q < 6; ++q) {
        unsigned long long bal = __ballot(p == q);
        if (lane == 0 && bal) atomicAdd(&cnt6[q], (unsigned int)__popcll(bal));
    }
    __syncthreads();
    if (tid == 0) {
        unsigned int a = 0;
        #pragma unroll
        for (int q = 0; q < 6; ++q) { off6[q] = a; pos6[q] = a; a += cnt6[q]; }
    }
    __syncthreads();
    // phase B: wave-aggregated placement into pair-grouped staging
    #pragma unroll
    for (int q = 0; q < 6; ++q) {
        unsigned long long bal = __ballot(p == q);
        if (bal) {
            int ldr = __builtin_ctzll(bal);
            unsigned int wb = 0;
            if (lane == ldr) wb = atomicAdd(&pos6[q], (unsigned int)__popcll(bal));
            wb = __shfl(wb, ldr, 64);
            if (p == q) {
                unsigned int s = wb + (unsigned int)__popcll(bal & ((1ull << lane) - 1ull));
                ex[s] = x; ey[s] = y; en[s] = (unsigned short)n;
            }
        }
    }
    __syncthreads();
    // flush grouped staging to this block's slab chunk + counts row
    {
        const unsigned int total = off6[5] + cnt6[5];
        const int gbase = blockIdx.x * KTHR;
        for (int k = tid; k < (int)total; k += KTHR) {
            xs[gbase + k] = ex[k];
            ys[gbase + k] = ey[k];
            ns[gbase + k] = (unsigned int)en[k];
        }
        if (tid < 6) counts[blockIdx.x * 6 + tid] = cnt6[tid];
    }
    // zero out+ok (36864 float4) and ksum = ksx|ksy|kcn (73728 f = 18432 f4)
    {
        float4* o4 = (float4*)out;
        for (int k = idx; k < 36864; k += KBLK * KTHR)
            o4[k] = make_float4(0.f, 0.f, 0.f, 0.f);
        float4* s4 = (float4*)ksum;
        for (int k = idx; k < 18432; k += KBLK * KTHR)
            s4[k] = make_float4(0.f, 0.f, 0.f, 0.f);
    }
}

// ---------------------------------------------------------------------------
__global__ __launch_bounds__(1024) void k_mid(
    const float* __restrict__ xs, const float* __restrict__ ys,
    const unsigned int* __restrict__ ns, const unsigned int* __restrict__ counts,
    float2* __restrict__ sps_g, unsigned int* __restrict__ cmb_g,
    unsigned int* __restrict__ cellpack_g, float* __restrict__ bbox_g,
    int* __restrict__ M_g,
    unsigned long long* __restrict__ ballots_g, unsigned int* __restrict__ base_g)
{
    const int p = blockIdx.x;
    const int tid = threadIdx.x, lane = tid & 63, wv = tid >> 6;

    __shared__ float2 sps[CAP];                 // 32 KB
    __shared__ unsigned int cmb[CAP];           // 16 KB
    __shared__ unsigned int cellpack[NCELL];    // 64 KB
    __shared__ unsigned short slist[CAP];       //  8 KB: ni-sorted PENDING idxs
    __shared__ unsigned long long pxb[128];     //  1 KB: pending-pixel bits
    __shared__ unsigned int woff[128];          // 512 B: rank prefix
    __shared__ unsigned long long ballots[64];
    __shared__ unsigned int base64[64];
    __shared__ unsigned int wtot[16];
    __shared__ float redbuf[4][16];
    __shared__ unsigned int csrc[KBLK], cdst[KBLK];
    __shared__ float sbminx, sbminy, scell;
    __shared__ int sM, sPC;

    for (int k = tid; k < CAP; k += 1024) cmb[k] = ST_U;
    for (int k = tid; k < NCELL; k += 1024) cellpack[k] = 0u;
    if (tid < 128) pxb[tid] = 0ull;

    // ---- chunk table: lane k of wave 0 owns source block k ----
    if (wv == 0) {
        unsigned int c6[6];
        #pragma unroll
        for (int q = 0; q < 6; ++q) c6[q] = counts[lane * 6 + q];
        unsigned int within = 0;
        for (int q = 0; q < p; ++q) within += c6[q];
        unsigned int len = c6[p];
        unsigned int v = len;
        for (int d = 1; d < 64; d <<= 1) {
            unsigned int u = __shfl_up(v, d, 64);
            if (lane >= d) v += u;
        }
        csrc[lane] = lane * KTHR + within;
        cdst[lane] = v - len;
        if (lane == 63) sM = (int)(v < CAP ? v : CAP);
    }
    __syncthreads();
    const int M = sM;

    // ---- gather compact entries into regs + bbox ----
    float xq[4], yq[4];
    unsigned int nq[4];
    int liq[4];
    {
        float mnx = 3e38f, mxx = -3e38f, mny = 3e38f, mxy = -3e38f;
        #pragma unroll
        for (int q = 0; q < 4; ++q) {
            int li = q * 1024 + tid;
            liq[q] = li;
            if (li < M) {
                int lo = 0, hi = KBLK - 1;          // last k with cdst[k] <= li
                #pragma unroll
                for (int s = 0; s < 6; ++s) {
                    int mid = (lo + hi + 1) >> 1;
                    if (cdst[mid] <= (unsigned int)li) lo = mid; else hi = mid - 1;
                }
                int si = csrc[lo] + (li - cdst[lo]);
                float x = xs[si], y = ys[si];
                xq[q] = x; yq[q] = y; nq[q] = ns[si];
                mnx = fminf(mnx, x); mxx = fmaxf(mxx, x);
                mny = fminf(mny, y); mxy = fmaxf(mxy, y);
            }
        }
        for (int d = 32; d; d >>= 1) {
            mnx = fminf(mnx, __shfl_xor(mnx, d, 64));
            mxx = fmaxf(mxx, __shfl_xor(mxx, d, 64));
            mny = fminf(mny, __shfl_xor(mny, d, 64));
            mxy = fmaxf(mxy, __shfl_xor(mxy, d, 64));
        }
        if (lane == 0) { redbuf[0][wv] = mnx; redbuf[1][wv] = mxx;
                         redbuf[2][wv] = mny; redbuf[3][wv] = mxy; }
    }
    __syncthreads();
    if (tid == 0) {
        float a = redbuf[0][0], b2 = redbuf[1][0], c = redbuf[2][0], d = redbuf[3][0];
        for (int q = 1; q < 16; ++q) {
            a = fminf(a, redbuf[0][q]); b2 = fmaxf(b2, redbuf[1][q]);
            c = fminf(c, redbuf[2][q]); d = fmaxf(d, redbuf[3][q]);
        }
        sbminx = a; sbminy = c;
        scell = fmaxf(2.0f * RAD, fmaxf(b2 - a, d - c) / 127.0f);  // cell >= 2*RAD
    }
    __syncthreads();
    const float bminx = sbminx, bminy = sbminy, inv = 1.0f / scell;

    // ---- grid count / scan / scatter (coords held in regs) ----
    int cellq[4];
    #pragma unroll
    for (int q = 0; q < 4; ++q) {
        if (liq[q] < M) {
            int ix = min(GRD - 1, max(0, (int)((xq[q] - bminx) * inv)));
            int iy = min(GRD - 1, max(0, (int)((yq[q] - bminy) * inv)));
            cellq[q] = iy * GRD + ix;
            atomicAdd(&cellpack[cellq[q]], 1u);
        } else cellq[q] = -1;
    }
    __syncthreads();
    {
        unsigned int c16[16], t16 = 0;          // thread owns 16 cells
        #pragma unroll
        for (int q = 0; q < 16; ++q) { c16[q] = cellpack[tid * 16 + q]; t16 += c16[q]; }
        unsigned int v = t16;
        for (int d = 1; d < 64; d <<= 1) {
            unsigned int u = __shfl_up(v, d, 64);
            if (lane >= d) v += u;
        }
        if (lane == 63) wtot[wv] = v;
        __syncthreads();
        if (tid == 0) {
            unsigned int acc = 0;
            for (int q = 0; q < 16; ++q) { unsigned int t = wtot[q]; wtot[q] = acc; acc += t; }
        }
        __syncthreads();
        unsigned int excl = wtot[wv] + v - t16;
        #pragma unroll
        for (int q = 0; q < 16; ++q) { cellpack[tid * 16 + q] = excl << 16; excl += c16[q]; }
    }
    __syncthreads();
    #pragma unroll
    for (int q = 0; q < 4; ++q) {
        if (cellq[q] >= 0) {
            unsigned int old = atomicAdd(&cellpack[cellq[q]], 1u);
            unsigned int pos = (old >> 16) + (old & 0xffffu);
            sps[pos] = make_float2(xq[q], yq[q]);
            cmb[pos] = (nq[q] << 2) | ST_U;
        }
    }   // cellpack now = start<<16 | cnt; sps/cmb grid-space
    __syncthreads();

    // ---- dump build state (sps/cellpack/bbox/M don't change after here) ----
    const int pb_ = p * CAP;
    for (int k = tid; k < CAP; k += 1024) sps_g[pb_ + k] = sps[k];
    for (int k = tid; k < NCELL; k += 1024) cellpack_g[p * NCELL + k] = cellpack[k];
    if (tid == 0) {
        bbox_g[p * 4 + 0] = bminx; bbox_g[p * 4 + 1] = bminy;
        bbox_g[p * 4 + 2] = inv;
        M_g[p] = M;
    }

    // flat window row scan over two contiguous streams (branchless)
    #define ROW_FLAGS(CY, CX0, CX1, NI, ME, DEAD, UNDEC)                          \
    {                                                                             \
        unsigned int wa = cellpack[(CY) * GRD + (CX0)];                           \
        unsigned int wb = cellpack[(CY) * GRD + (CX1)];                           \
        unsigned int f0 = wa >> 16, f1 = (wb >> 16) + (wb & 0xffffu);             \
        for (unsigned int f = f0; f < f1; ++f) {                                  \
            unsigned int wf = cmb[f];                                             \
            float2 q = sps[f];                                                    \
            float dx = __fsub_rn((ME).x, q.x), dy = __fsub_rn((ME).y, q.y);       \
            float d2 = __fadd_rn(__fmul_rn(dx, dx), __fmul_rn(dy, dy));           \
            bool in = (d2 < R2) & ((int)(wf >> 2) < (NI));                        \
            DEAD  |= in & ((wf & 3u) == ST_A);                                    \
            UNDEC |= in & ((wf & 3u) == ST_U);                                    \
        }                                                                         \
    }

    // ---- round 0: 16-wave full sweep (statuses only; no pending list) ----
    for (int e = tid; e < M; e += 1024) {
        unsigned int w = cmb[e];
        int ni = (int)(w >> 2);
        float2 me = sps[e];
        int cx0 = max(0, (int)((me.x - RAD - bminx) * inv));
        int cx1 = min(GRD - 1, (int)((me.x + RAD - bminx) * inv));
        int cy0 = max(0, (int)((me.y - RAD - bminy) * inv));
        int cy1 = min(GRD - 1, (int)((me.y + RAD - bminy) * inv));
        bool dead = false, undec = false;
        ROW_FLAGS(cy0, cx0, cx1, ni, me, dead, undec);
        if (cy1 > cy0) ROW_FLAGS(cy1, cx0, cx1, ni, me, dead, undec);
        if (dead) cmb[e] = (w & ~3u) | ST_D;
        else if (!undec) cmb[e] = (w & ~3u) | ST_A;
    }
    __syncthreads();

    // ---- pending bitmask by pixel + rank prefix + slist scatter ----
    for (int e = tid; e < M; e += 1024) {
        unsigned int w = cmb[e];
        if ((w & 3u) == ST_U) {
            unsigned int n = w >> 2;
            atomicOr(&pxb[n >> 6], 1ull << (n & 63));
        }
    }
    __syncthreads();
    if (wv == 0) {
        unsigned int c0 = (unsigned int)__popcll(pxb[2 * lane]);
        unsigned int c1 = (unsigned int)__popcll(pxb[2 * lane + 1]);
        unsigned int s = c0 + c1, v = s;
        for (int d = 1; d < 64; d <<= 1) {
            unsigned int u = __shfl_up(v, d, 64);
            if (lane >= d) v += u;
        }
        woff[2 * lane] = v - s;
        woff[2 * lane + 1] = v - c1;
        if (lane == 63) sPC = (int)v;
    }
    __syncthreads();
    for (int e = tid; e < M; e += 1024) {
        unsigned int w = cmb[e];
        if ((w & 3u) == ST_U) {
            unsigned int n = w >> 2;
            int r = (int)woff[n >> 6] +
                    (int)__popcll(pxb[n >> 6] & ((1ull << (n & 63)) - 1ull));
            slist[r] = (unsigned short)e;
        }
    }
    __syncthreads();

    // ---- chunk-serial resolution of pending on wave 0 (exact; batched) ----
    // Earlier chunks finalized in program order; U & nf<ni => same chunk
    // (earlier-chunk pending already written A/D before this chunk's scan).
    #define SER_ROW8(CY, CX0, CX1, NI, ME, EXTD, NBR, CC)                         \
    {                                                                             \
        unsigned int wa = cellpack[(CY) * GRD + (CX0)];                           \
        unsigned int wb = cellpack[(CY) * GRD + (CX1)];                           \
        unsigned int f0 = wa >> 16, f1 = (wb >> 16) + (wb & 0xffffu);             \
        for (unsigned int f = f0; f < f1; f += 8) {                               \
            unsigned int ff[8]; unsigned int wf[8]; float2 qq[8];                 \
            _Pragma("unroll")                                                     \
            for (int t = 0; t < 8; ++t) ff[t] = (f + t < f1) ? f + t : f0;        \
            _Pragma("unroll")                                                     \
            for (int t = 0; t < 8; ++t) wf[t] = cmb[ff[t]];                       \
            _Pragma("unroll")                                                     \
            for (int t = 0; t < 8; ++t) qq[t] = sps[ff[t]];                       \
            _Pragma("unroll")                                                     \
            for (int t = 0; t < 8; ++t) {                                         \
                bool V = (t == 0) | (f + t < f1);                                 \
                float dx = __fsub_rn((ME).x, qq[t].x);                            \
                float dy = __fsub_rn((ME).y, qq[t].y);                            \
                float d2 = __fadd_rn(__fmul_rn(dx, dx), __fmul_rn(dy, dy));       \
                int nf = (int)(wf[t] >> 2);                                       \
                bool in = V & (d2 < R2) & (nf < (NI));                            \
                unsigned int st = wf[t] & 3u;                                     \
                EXTD |= in & (st == ST_A);                                        \
                if (in && st == ST_U) {                                           \
                    int rf = (int)woff[nf >> 6] +                                 \
                        (int)__popcll(pxb[nf >> 6] & ((1ull << (nf & 63)) - 1ull));\
                    if ((rf >> 6) == (CC)) NBR |= 1ull << (rf & 63);              \
                }                                                                 \
            }                                                                     \
        }                                                                         \
    }
    if (wv == 0) {
        const int PC = sPC;
        for (int c = 0; (c << 6) < PC; ++c) {
            int i = (c << 6) + lane;
            bool act = i < PC;
            int e = act ? (int)slist[i] : 0;
            unsigned int w = cmb[e];
            int ni = (int)(w >> 2);
            float2 me = sps[e];
            bool extdead = false;
            unsigned long long nbr = 0ull;
            if (act) {
                int cx0 = max(0, (int)((me.x - RAD - bminx) * inv));
                int cx1 = min(GRD - 1, (int)((me.x + RAD - bminx) * inv));
                int cy0 = max(0, (int)((me.y - RAD - bminy) * inv));
                int cy1 = min(GRD - 1, (int)((me.y + RAD - bminy) * inv));
                SER_ROW8(cy0, cx0, cx1, ni, me, extdead, nbr, c);
                if (cy1 > cy0) SER_ROW8(cy1, cx0, cx1, ni, me, extdead, nbr, c);
            }
            // ballot resolve (R25 field-verified): nbr ⊆ lower same-chunk lanes
            bool decided = !act, kept = false;
            unsigned long long decidedM = __ballot(decided);
            unsigned long long keptM = 0ull;
            while (decidedM != ~0ull) {
                bool dienow = !decided && (extdead || ((nbr & keptM) != 0ull));
                bool keepnow = !decided && !dienow && ((nbr & ~decidedM) == 0ull);
                unsigned long long dM = __ballot(dienow);
                unsigned long long kM = __ballot(keepnow);
                keptM |= kM;
                decidedM |= dM | kM;
                decided = decided || dienow || keepnow;
                kept = kept || keepnow;
            }
            if (act) cmb[e] = (w & ~3u) | (kept ? ST_A : ST_D);
        }
    }
    __syncthreads();

    // ---- kept-rank: ballot bitmask + wave-scanned prefix; dump cmb + rank ----
    for (int k = 0; k < 4; ++k) {
        int e = (k << 10) + tid;
        unsigned long long bal = __ballot((cmb[e] & 3u) == ST_A);  // e>=M stays U
        if (lane == 0) ballots[(k << 4) + wv] = bal;
    }
    __syncthreads();
    if (wv == 0) {
        unsigned int s = (unsigned int)__popcll(ballots[lane]);
        unsigned int v = s;
        for (int d = 1; d < 64; d <<= 1) {
            unsigned int u = __shfl_up(v, d, 64);
            if (lane >= d) v += u;
        }
        base64[lane] = v - s;
    }
    __syncthreads();
    for (int k = tid; k < CAP; k += 1024) cmb_g[pb_ + k] = cmb[k];
    if (tid < 64) { ballots_g[(p << 6) + tid] = ballots[tid]; base_g[(p << 6) + tid] = base64[tid]; }
}

#define KRANK_G(P, E) ((int)base_g[((P) << 6) + ((E) >> 6)] +                     \
    __popcll(ballots_g[((P) << 6) + ((E) >> 6)] & ((1ull << ((E) & 63)) - 1ull)))

// ---------------------------------------------------------------------------
__global__ __launch_bounds__(WTHR) void k_assign(
    const float2* __restrict__ sps_g, const unsigned int* __restrict__ cmb_g,
    const unsigned int* __restrict__ cellpack_g, const float* __restrict__ bbox_g,
    const int* __restrict__ M_g,
    const unsigned long long* __restrict__ ballots_g, const unsigned int* __restrict__ base_g,
    float* __restrict__ ksx, float* __restrict__ ksy, float* __restrict__ kcn)
{
    const int p = blockIdx.x / NSL, s = blockIdx.x % NSL;
    const int tid = threadIdx.x;
    const int M = M_g[p];
    const float bminx = bbox_g[p * 4], bminy = bbox_g[p * 4 + 1], inv = bbox_g[p * 4 + 2];
    const float2* sp = sps_g + p * CAP;
    const unsigned int* cm = cmb_g + p * CAP;
    const unsigned int* cp = cellpack_g + p * NCELL;

    const int chunk = (M + NSL - 1) / NSL;
    const int e0 = s * chunk, e1 = min(M, e0 + chunk);

    #define G_ROW_ARGMIN(CY, CX0, CX1, ME, BD, BE, BN)                            \
    {                                                                             \
        unsigned int wa = cp[(CY) * GRD + (CX0)];                                 \
        unsigned int wb = cp[(CY) * GRD + (CX1)];                                 \
        unsigned int f0 = wa >> 16, f1 = (wb >> 16) + (wb & 0xffffu);             \
        for (unsigned int f = f0; f < f1; ++f) {                                  \
            unsigned int wf = cm[f];                                              \
            float2 q = sp[f];                                                     \
            float dx = __fsub_rn((ME).x, q.x), dy = __fsub_rn((ME).y, q.y);       \
            float d2 = __fadd_rn(__fmul_rn(dx, dx), __fmul_rn(dy, dy));           \
            int nf = (int)(wf >> 2);                                              \
            bool better = ((wf & 3u) == ST_A) &                                   \
                          ((d2 < BD) | ((d2 == BD) & (nf < BN)));                 \
            BD = better ? d2 : BD;                                                \
            BE = better ? (int)f : BE;                                            \
            BN = better ? nf : BN;                                                \
        }                                                                         \
    }
    for (int e = e0 + tid; e < e1; e += WTHR) {
        unsigned int w = cm[e];
        float2 me = sp[e];
        int be;
        if ((w & 3u) == ST_A) {
            be = e;                              // self: unique d2 = 0
        } else {
            int cx0 = max(0, (int)((me.x - RAD - bminx) * inv));
            int cx1 = min(GRD - 1, (int)((me.x + RAD - bminx) * inv));
            int cy0 = max(0, (int)((me.y - RAD - bminy) * inv));
            int cy1 = min(GRD - 1, (int)((me.y + RAD - bminy) * inv));
            float bd = 3e38f;
            be = -1;
            int bn = 1 << 30;
            G_ROW_ARGMIN(cy0, cx0, cx1, me, bd, be, bn);
            if (cy1 > cy0) G_ROW_ARGMIN(cy1, cx0, cx1, me, bd, be, bn);
            if (be < 0) continue;
        }
        int r = KRANK_G(p, be);
        atomicAdd(&ksx[p * CAP + r], me.x);
        atomicAdd(&ksy[p * CAP + r], me.y);
        atomicAdd(&kcn[p * CAP + r], 1.0f);
    }
}

// ---------------------------------------------------------------------------
__global__ __launch_bounds__(WTHR) void k_out(
    const unsigned int* __restrict__ cmb_g, const int* __restrict__ M_g,
    const unsigned long long* __restrict__ ballots_g, const unsigned int* __restrict__ base_g,
    const float* __restrict__ ksx, const float* __restrict__ ksy,
    const float* __restrict__ kcn, float* __restrict__ out)
{
    const int p = blockIdx.x / NSL, s = blockIdx.x % NSL;
    const int tid = threadIdx.x;
    const int M = M_g[p];
    const unsigned int* cm = cmb_g + p * CAP;
    const int base = p * NPTS;
    float* ok = out + (size_t)2 * NP * NPTS + base;

    const int chunk = (M + NSL - 1) / NSL;
    const int e0 = s * chunk, e1 = min(M, e0 + chunk);

    for (int e = e0 + tid; e < e1; e += WTHR) {
        unsigned int w = cm[e];
        if ((w & 3u) != ST_A) continue;
        int n = (int)(w >> 2);
        int r = KRANK_G(p, e);
        float c = kcn[p * CAP + r];
        out[2 * (base + n)]     = ksx[p * CAP + r] / c;   // c >= 1 (self-assign)
        out[2 * (base + n) + 1] = ksy[p * CAP + r] / c;
        ok[n] = 1.0f;
    }
}

// ---------------------------------------------------------------------------
extern "C" void kernel_launch(void* const* d_in, const int* in_sizes, int n_in,
                              void* d_out, int out_size, void* d_ws, size_t ws_size,
                              hipStream_t stream) {
    const float* seg   = (const float*)d_in[0];   // [B,C,H,W] f32
    const float* lidar = (const float*)d_in[1];   // [B,2,H,W] f32
    float* out = (float*)d_out;
    float* wsf = (float*)d_ws;

    float* xs = wsf;                                          // 16384
    float* ys = wsf + 16384;                                  // 16384
    unsigned int* ns = (unsigned int*)(wsf + 32768);          // 16384
    unsigned int* counts = (unsigned int*)(wsf + 49152);      // 384
    float2* sps_g = (float2*)(wsf + 49536);                   // 6*4096 f2 -> 98688
    unsigned int* cmb_g = (unsigned int*)(wsf + 98688);       // 24576    -> 123264
    unsigned int* cellpack_g = (unsigned int*)(wsf + 123264); // 98304    -> 221568
    float* bbox_g = wsf + 221568;                             // 24
    int* M_g = (int*)(wsf + 221592);                          // 6 (+2 pad)
    unsigned long long* ballots_g = (unsigned long long*)(wsf + 221600); // 384 u64
    unsigned int* base_g = (unsigned int*)(wsf + 222368);     // 384
    float* ksx = wsf + 222752;                                // 24576
    float* ksy = wsf + 247328;                                // 24576
    float* kcn = wsf + 271904;                                // 24576

    k_front <<<KBLK, KTHR, 0, stream>>>(seg, lidar, xs, ys, ns, counts, ksx, out);
    k_mid   <<<NP, 1024, 0, stream>>>(xs, ys, ns, counts, sps_g, cmb_g, cellpack_g,
                                      bbox_g, M_g, ballots_g, base_g);
    k_assign<<<WBLK, WTHR, 0, stream>>>(sps_g, cmb_g, cellpack_g, bbox_g, M_g,
                                        ballots_g, base_g, ksx, ksy, kcn);
    k_out   <<<WBLK, WTHR, 0, stream>>>(cmb_g, M_g, ballots_g, base_g, ksx, ksy, kcn, out);
}

// Round 14
// 100.713 us; speedup vs baseline: 1.8250x; 1.3274x over previous
//
#include <hip/hip_runtime.h>

#define NPTS 8192      // H*W
#define BCLS 4         // C
#define NP   6         // B*(C-1) pairs
#define R2   9.0f
#define RAD  3.0f
#define GRD  128       // fine grid — cell = max(6, span/127) ~= 2*RAD
#define NCELL (GRD*GRD)
#define PCAP 2048      // pending-list capacity (overflow -> sweep fallback)
#define CAP  4096      // per-pair compact-point capacity (M ~ 2048 +- 40)
#define KBLK 64        // front kernel blocks
#define KTHR 256       // front kernel threads (KBLK*KTHR == B*NPTS)
#define NSL  8         // slices per pair for wide kernels
#define WBLK (NP*NSL)  // 48 wide blocks
#define WTHR 256

#define ST_U 0u
#define ST_A 1u
#define ST_D 2u

// ---------------------------------------------------------------------------
// R27 = R23 verbatim (session best: 101.57 us). Terminal validation run.
// R26 post-mortem: hybrid chunk-serial pending (68us) still 1.7x worse than
// the plain parallel fixpoint — serial-exact NMS refuted in pure (R25: 119us)
// and hybrid (R26) forms; single-wave LDS latency cannot be batched away.
// Exhausted levers: round machinery (R14/15/16), scan MLP (R17), scan volume
// (R20: GRD=128, the +4.4us win), intra-round rescans (R22), wave ordering
// (R24), phase fission (R18/19/23). Floor decomposition: harness re-poison
// fill ~40us AT 84% HBM PEAK (its own roofline, uncontrollable) + ~10us
// launch overhead + ~10us wide kernels + k_mid ~40us (build+dumps ~12,
// round-0 ~3, serial-chain fixpoint ~25 — every parallelization of which
// measured flat or worse). Prediction: total 101.6 +- 1.5.
// ---------------------------------------------------------------------------

__global__ __launch_bounds__(KTHR) void k_front(
    const float* __restrict__ seg, const float* __restrict__ lidar,
    float* __restrict__ xs, float* __restrict__ ys,
    unsigned int* __restrict__ ns, unsigned int* __restrict__ counts,
    float* __restrict__ ksum, float* __restrict__ out)
{
    const int tid = threadIdx.x, lane = tid & 63;
    const int idx = blockIdx.x * KTHR + tid;       // [0, B*NPTS)
    const int b = idx >> 13, n = idx & 8191;

    __shared__ float ex[KTHR], ey[KTHR];
    __shared__ unsigned short en[KTHR];
    __shared__ unsigned int cnt6[6], off6[6], pos6[6];

    if (tid < 6) cnt6[tid] = 0;
    __syncthreads();

    // per-pixel argmax (strict >: first index wins ties)
    const float* segb = seg + (size_t)b * BCLS * NPTS + n;
    float bv = segb[0];
    int bc = 0;
    #pragma unroll
    for (int c = 1; c < BCLS; ++c) {
        float v = segb[(size_t)c * NPTS];
        if (v > bv) { bv = v; bc = c; }
    }
    const float x = lidar[(size_t)b * 2 * NPTS + n];
    const float y = lidar[(size_t)b * 2 * NPTS + NPTS + n];
    const int p = (bc > 0) ? (b * 3 + bc - 1) : -1;

    // phase A: wave-aggregated per-pair counts
    #pragma unroll
    for (int q = 0; q < 6; ++q) {
        unsigned long long bal = __ballot(p == q);
        if (lane == 0 && bal) atomicAdd(&cnt6[q], (unsigned int)__popcll(bal));
    }
    __syncthreads();
    if (tid == 0) {
        unsigned int a = 0;
        #pragma unroll
        for (int q = 0; q < 6; ++q) { off6[q] = a; pos6[q] = a; a += cnt6[q]; }
    }
    __syncthreads();
    // phase B: wave-aggregated placement into pair-grouped staging
    #pragma unroll
    for (int q = 0; q < 6; ++q) {
        unsigned long long bal = __ballot(p == q);
        if (bal) {
            int ldr = __builtin_ctzll(bal);
            unsigned int wb = 0;
            if (lane == ldr) wb = atomicAdd(&pos6[q], (unsigned int)__popcll(bal));
            wb = __shfl(wb, ldr, 64);
            if (p == q) {
                unsigned int s = wb + (unsigned int)__popcll(bal & ((1ull << lane) - 1ull));
                ex[s] = x; ey[s] = y; en[s] = (unsigned short)n;
            }
        }
    }
    __syncthreads();
    // flush grouped staging to this block's slab chunk + counts row
    {
        const unsigned int total = off6[5] + cnt6[5];
        const int gbase = blockIdx.x * KTHR;
        for (int k = tid; k < (int)total; k += KTHR) {
            xs[gbase + k] = ex[k];
            ys[gbase + k] = ey[k];
            ns[gbase + k] = (unsigned int)en[k];
        }
        if (tid < 6) counts[blockIdx.x * 6 + tid] = cnt6[tid];
    }
    // zero out+ok (36864 float4) and ksum = ksx|ksy|kcn (73728 f = 18432 f4)
    {
        float4* o4 = (float4*)out;
        for (int k = idx; k < 36864; k += KBLK * KTHR)
            o4[k] = make_float4(0.f, 0.f, 0.f, 0.f);
        float4* s4 = (float4*)ksum;
        for (int k = idx; k < 18432; k += KBLK * KTHR)
            s4[k] = make_float4(0.f, 0.f, 0.f, 0.f);
    }
}

// ---------------------------------------------------------------------------
__global__ __launch_bounds__(1024) void k_mid(
    const float* __restrict__ xs, const float* __restrict__ ys,
    const unsigned int* __restrict__ ns, const unsigned int* __restrict__ counts,
    float2* __restrict__ sps_g, unsigned int* __restrict__ cmb_g,
    unsigned int* __restrict__ cellpack_g, float* __restrict__ bbox_g,
    int* __restrict__ M_g,
    unsigned long long* __restrict__ ballots_g, unsigned int* __restrict__ base_g)
{
    const int p = blockIdx.x;
    const int tid = threadIdx.x, lane = tid & 63, wv = tid >> 6;

    __shared__ float2 sps[CAP];                 // 32 KB
    __shared__ unsigned int cmb[CAP];           // 16 KB
    __shared__ unsigned int cellpack[NCELL];    // 64 KB
    __shared__ unsigned short plist[2][PCAP];   //  8 KB
    __shared__ int pcnt[2];
    __shared__ unsigned long long ballots[64];
    __shared__ unsigned int base64[64];
    __shared__ unsigned int wtot[16];
    __shared__ float redbuf[4][16];
    __shared__ unsigned int csrc[KBLK], cdst[KBLK];
    __shared__ float sbminx, sbminy, scell;
    __shared__ int sM;

    for (int k = tid; k < CAP; k += 1024) cmb[k] = ST_U;
    for (int k = tid; k < NCELL; k += 1024) cellpack[k] = 0u;
    if (tid == 0) { pcnt[0] = 0; pcnt[1] = 0; }

    // ---- chunk table: lane k of wave 0 owns source block k ----
    if (wv == 0) {
        unsigned int c6[6];
        #pragma unroll
        for (int q = 0; q < 6; ++q) c6[q] = counts[lane * 6 + q];
        unsigned int within = 0;
        for (int q = 0; q < p; ++q) within += c6[q];
        unsigned int len = c6[p];
        unsigned int v = len;
        for (int d = 1; d < 64; d <<= 1) {
            unsigned int u = __shfl_up(v, d, 64);
            if (lane >= d) v += u;
        }
        csrc[lane] = lane * KTHR + within;
        cdst[lane] = v - len;
        if (lane == 63) sM = (int)(v < CAP ? v : CAP);
    }
    __syncthreads();
    const int M = sM;

    // ---- gather compact entries into regs + bbox ----
    float xq[4], yq[4];
    unsigned int nq[4];
    int liq[4];
    {
        float mnx = 3e38f, mxx = -3e38f, mny = 3e38f, mxy = -3e38f;
        #pragma unroll
        for (int q = 0; q < 4; ++q) {
            int li = q * 1024 + tid;
            liq[q] = li;
            if (li < M) {
                int lo = 0, hi = KBLK - 1;          // last k with cdst[k] <= li
                #pragma unroll
                for (int s = 0; s < 6; ++s) {
                    int mid = (lo + hi + 1) >> 1;
                    if (cdst[mid] <= (unsigned int)li) lo = mid; else hi = mid - 1;
                }
                int si = csrc[lo] + (li - cdst[lo]);
                float x = xs[si], y = ys[si];
                xq[q] = x; yq[q] = y; nq[q] = ns[si];
                mnx = fminf(mnx, x); mxx = fmaxf(mxx, x);
                mny = fminf(mny, y); mxy = fmaxf(mxy, y);
            }
        }
        for (int d = 32; d; d >>= 1) {
            mnx = fminf(mnx, __shfl_xor(mnx, d, 64));
            mxx = fmaxf(mxx, __shfl_xor(mxx, d, 64));
            mny = fminf(mny, __shfl_xor(mny, d, 64));
            mxy = fmaxf(mxy, __shfl_xor(mxy, d, 64));
        }
        if (lane == 0) { redbuf[0][wv] = mnx; redbuf[1][wv] = mxx;
                         redbuf[2][wv] = mny; redbuf[3][wv] = mxy; }
    }
    __syncthreads();
    if (tid == 0) {
        float a = redbuf[0][0], b2 = redbuf[1][0], c = redbuf[2][0], d = redbuf[3][0];
        for (int q = 1; q < 16; ++q) {
            a = fminf(a, redbuf[0][q]); b2 = fmaxf(b2, redbuf[1][q]);
            c = fminf(c, redbuf[2][q]); d = fmaxf(d, redbuf[3][q]);
        }
        sbminx = a; sbminy = c;
        scell = fmaxf(2.0f * RAD, fmaxf(b2 - a, d - c) / 127.0f);  // cell >= 2*RAD
    }
    __syncthreads();
    const float bminx = sbminx, bminy = sbminy, inv = 1.0f / scell;

    // ---- grid count / scan / scatter (coords held in regs) ----
    int cellq[4];
    #pragma unroll
    for (int q = 0; q < 4; ++q) {
        if (liq[q] < M) {
            int ix = min(GRD - 1, max(0, (int)((xq[q] - bminx) * inv)));
            int iy = min(GRD - 1, max(0, (int)((yq[q] - bminy) * inv)));
            cellq[q] = iy * GRD + ix;
            atomicAdd(&cellpack[cellq[q]], 1u);
        } else cellq[q] = -1;
    }
    __syncthreads();
    {
        unsigned int c16[16], t16 = 0;          // thread owns 16 cells
        #pragma unroll
        for (int q = 0; q < 16; ++q) { c16[q] = cellpack[tid * 16 + q]; t16 += c16[q]; }
        unsigned int v = t16;
        for (int d = 1; d < 64; d <<= 1) {
            unsigned int u = __shfl_up(v, d, 64);
            if (lane >= d) v += u;
        }
        if (lane == 63) wtot[wv] = v;
        __syncthreads();
        if (tid == 0) {
            unsigned int acc = 0;
            for (int q = 0; q < 16; ++q) { unsigned int t = wtot[q]; wtot[q] = acc; acc += t; }
        }
        __syncthreads();
        unsigned int excl = wtot[wv] + v - t16;
        #pragma unroll
        for (int q = 0; q < 16; ++q) { cellpack[tid * 16 + q] = excl << 16; excl += c16[q]; }
    }
    __syncthreads();
    #pragma unroll
    for (int q = 0; q < 4; ++q) {
        if (cellq[q] >= 0) {
            unsigned int old = atomicAdd(&cellpack[cellq[q]], 1u);
            unsigned int pos = (old >> 16) + (old & 0xffffu);
            sps[pos] = make_float2(xq[q], yq[q]);
            cmb[pos] = (nq[q] << 2) | ST_U;
        }
    }   // cellpack now = start<<16 | cnt; sps/cmb grid-space
    __syncthreads();

    // ---- dump build state (sps/cellpack/bbox/M don't change after here) ----
    const int pb = p * CAP;
    for (int k = tid; k < CAP; k += 1024) sps_g[pb + k] = sps[k];
    for (int k = tid; k < NCELL; k += 1024) cellpack_g[p * NCELL + k] = cellpack[k];
    if (tid == 0) {
        bbox_g[p * 4 + 0] = bminx; bbox_g[p * 4 + 1] = bminy;
        bbox_g[p * 4 + 2] = inv;
        M_g[p] = M;
    }

    // flat window row scan over two contiguous streams (branchless)
    #define ROW_FLAGS(CY, CX0, CX1, NI, ME, DEAD, UNDEC)                          \
    {                                                                             \
        unsigned int wa = cellpack[(CY) * GRD + (CX0)];                           \
        unsigned int wb = cellpack[(CY) * GRD + (CX1)];                           \
        unsigned int f0 = wa >> 16, f1 = (wb >> 16) + (wb & 0xffffu);             \
        for (unsigned int f = f0; f < f1; ++f) {                                  \
            unsigned int wf = cmb[f];                                             \
            float2 q = sps[f];                                                    \
            float dx = __fsub_rn((ME).x, q.x), dy = __fsub_rn((ME).y, q.y);       \
            float d2 = __fadd_rn(__fmul_rn(dx, dx), __fmul_rn(dy, dy));           \
            bool in = (d2 < R2) & ((int)(wf >> 2) < (NI));                        \
            DEAD  |= in & ((wf & 3u) == ST_A);                                    \
            UNDEC |= in & ((wf & 3u) == ST_U);                                    \
        }                                                                         \
    }
    #define SCAN_FLAGS(NI, ME, DEAD, UNDEC)                                       \
    {                                                                             \
        int cx0 = max(0, (int)(((ME).x - RAD - bminx) * inv));                    \
        int cx1 = min(GRD - 1, (int)(((ME).x + RAD - bminx) * inv));              \
        int cy0 = max(0, (int)(((ME).y - RAD - bminy) * inv));                    \
        int cy1 = min(GRD - 1, (int)(((ME).y + RAD - bminy) * inv));              \
        DEAD = false; UNDEC = false;                                              \
        ROW_FLAGS(cy0, cx0, cx1, NI, ME, DEAD, UNDEC);                            \
        if (cy1 > cy0) ROW_FLAGS(cy1, cx0, cx1, NI, ME, DEAD, UNDEC);             \
    }

    // ---- P4 round 0: full sweep (grid order), wave-ordered pending append ----
    for (int e = tid; e < M; e += 1024) {
        unsigned int w = cmb[e];
        int ni = (int)(w >> 2);
        float2 me = sps[e];
        bool dead, undec;
        SCAN_FLAGS(ni, me, dead, undec);
        if (dead) cmb[e] = (w & ~3u) | ST_D;
        else if (!undec) cmb[e] = (w & ~3u) | ST_A;
        bool pendf = !dead && undec;
        unsigned long long act = __ballot(true);
        unsigned long long bal = __ballot(pendf);
        int leader = __builtin_ctzll(act);
        int cnt = __popcll(bal);
        int wbase = 0;
        if (lane == leader && cnt) wbase = atomicAdd(&pcnt[0], cnt);
        wbase = __shfl(wbase, leader, 64);
        if (pendf) {
            int pos = wbase + __popcll(bal & ((1ull << lane) - 1ull));
            if (pos < PCAP) plist[0][pos] = (unsigned short)e;
        }
    }

    // ---- P4 rounds over compacted pending (proven R11 engine) ----
    int cur = 0;
    for (int round = 0; round < NPTS; ++round) {
        __syncthreads();
        int pc = pcnt[cur];
        if (pc == 0) break;
        if (pc > PCAP) {                        // overflow fallback: full sweeps
            for (;;) {
                bool any = false;
                __syncthreads();
                for (int e = tid; e < M; e += 1024) {
                    unsigned int w = cmb[e];
                    if ((w & 3u) != ST_U) continue;
                    int ni = (int)(w >> 2);
                    float2 me = sps[e];
                    bool dead, undec;
                    SCAN_FLAGS(ni, me, dead, undec);
                    if (dead) cmb[e] = (w & ~3u) | ST_D;
                    else if (!undec) cmb[e] = (w & ~3u) | ST_A;
                    else any = true;
                }
                if (__syncthreads_count(any) == 0) break;
            }
            break;
        }
        if (tid == 0) pcnt[cur ^ 1] = 0;
        __syncthreads();
        for (int idx = tid; idx < pc; idx += 1024) {
            int e = plist[cur][idx];
            unsigned int w = cmb[e];
            int ni = (int)(w >> 2);
            float2 me = sps[e];
            bool dead, undec;
            SCAN_FLAGS(ni, me, dead, undec);
            if (dead) cmb[e] = (w & ~3u) | ST_D;
            else if (!undec) cmb[e] = (w & ~3u) | ST_A;
            bool pendf = !dead && undec;
            unsigned long long act = __ballot(true);
            unsigned long long bal = __ballot(pendf);
            int leader = __builtin_ctzll(act);
            int cnt = __popcll(bal);
            int wbase = 0;
            if (lane == leader && cnt) wbase = atomicAdd(&pcnt[cur ^ 1], cnt);
            wbase = __shfl(wbase, leader, 64);
            if (pendf) {
                int pos = wbase + __popcll(bal & ((1ull << lane) - 1ull));
                if (pos < PCAP) plist[cur ^ 1][pos] = (unsigned short)e;
            }
        }
        cur ^= 1;
    }
    __syncthreads();

    // ---- kept-rank: ballot bitmask + wave-scanned prefix; dump cmb + rank ----
    for (int k = 0; k < 4; ++k) {
        int e = (k << 10) + tid;
        unsigned long long bal = __ballot((cmb[e] & 3u) == ST_A);  // e>=M stays U
        if (lane == 0) ballots[(k << 4) + wv] = bal;
    }
    __syncthreads();
    if (wv == 0) {
        unsigned int s = (unsigned int)__popcll(ballots[lane]);
        unsigned int v = s;
        for (int d = 1; d < 64; d <<= 1) {
            unsigned int u = __shfl_up(v, d, 64);
            if (lane >= d) v += u;
        }
        base64[lane] = v - s;
    }
    __syncthreads();
    for (int k = tid; k < CAP; k += 1024) cmb_g[pb + k] = cmb[k];
    if (tid < 64) { ballots_g[(p << 6) + tid] = ballots[tid]; base_g[(p << 6) + tid] = base64[tid]; }
}

#define KRANK_G(P, E) ((int)base_g[((P) << 6) + ((E) >> 6)] +                     \
    __popcll(ballots_g[((P) << 6) + ((E) >> 6)] & ((1ull << ((E) & 63)) - 1ull)))

// ---------------------------------------------------------------------------
__global__ __launch_bounds__(WTHR) void k_assign(
    const float2* __restrict__ sps_g, const unsigned int* __restrict__ cmb_g,
    const unsigned int* __restrict__ cellpack_g, const float* __restrict__ bbox_g,
    const int* __restrict__ M_g,
    const unsigned long long* __restrict__ ballots_g, const unsigned int* __restrict__ base_g,
    float* __restrict__ ksx, float* __restrict__ ksy, float* __restrict__ kcn)
{
    const int p = blockIdx.x / NSL, s = blockIdx.x % NSL;
    const int tid = threadIdx.x;
    const int M = M_g[p];
    const float bminx = bbox_g[p * 4], bminy = bbox_g[p * 4 + 1], inv = bbox_g[p * 4 + 2];
    const float2* sp = sps_g + p * CAP;
    const unsigned int* cm = cmb_g + p * CAP;
    const unsigned int* cp = cellpack_g + p * NCELL;

    const int chunk = (M + NSL - 1) / NSL;
    const int e0 = s * chunk, e1 = min(M, e0 + chunk);

    #define G_ROW_ARGMIN(CY, CX0, CX1, ME, BD, BE, BN)                            \
    {                                                                             \
        unsigned int wa = cp[(CY) * GRD + (CX0)];                                 \
        unsigned int wb = cp[(CY) * GRD + (CX1)];                                 \
        unsigned int f0 = wa >> 16, f1 = (wb >> 16) + (wb & 0xffffu);             \
        for (unsigned int f = f0; f < f1; ++f) {                                  \
            unsigned int wf = cm[f];                                              \
            float2 q = sp[f];                                                     \
            float dx = __fsub_rn((ME).x, q.x), dy = __fsub_rn((ME).y, q.y);       \
            float d2 = __fadd_rn(__fmul_rn(dx, dx), __fmul_rn(dy, dy));           \
            int nf = (int)(wf >> 2);                                              \
            bool better = ((wf & 3u) == ST_A) &                                   \
                          ((d2 < BD) | ((d2 == BD) & (nf < BN)));                 \
            BD = better ? d2 : BD;                                                \
            BE = better ? (int)f : BE;                                            \
            BN = better ? nf : BN;                                                \
        }                                                                         \
    }
    for (int e = e0 + tid; e < e1; e += WTHR) {
        unsigned int w = cm[e];
        float2 me = sp[e];
        int be;
        if ((w & 3u) == ST_A) {
            be = e;                              // self: unique d2 = 0
        } else {
            int cx0 = max(0, (int)((me.x - RAD - bminx) * inv));
            int cx1 = min(GRD - 1, (int)((me.x + RAD - bminx) * inv));
            int cy0 = max(0, (int)((me.y - RAD - bminy) * inv));
            int cy1 = min(GRD - 1, (int)((me.y + RAD - bminy) * inv));
            float bd = 3e38f;
            be = -1;
            int bn = 1 << 30;
            G_ROW_ARGMIN(cy0, cx0, cx1, me, bd, be, bn);
            if (cy1 > cy0) G_ROW_ARGMIN(cy1, cx0, cx1, me, bd, be, bn);
            if (be < 0) continue;
        }
        int r = KRANK_G(p, be);
        atomicAdd(&ksx[p * CAP + r], me.x);
        atomicAdd(&ksy[p * CAP + r], me.y);
        atomicAdd(&kcn[p * CAP + r], 1.0f);
    }
}

// ---------------------------------------------------------------------------
__global__ __launch_bounds__(WTHR) void k_out(
    const unsigned int* __restrict__ cmb_g, const int* __restrict__ M_g,
    const unsigned long long* __restrict__ ballots_g, const unsigned int* __restrict__ base_g,
    const float* __restrict__ ksx, const float* __restrict__ ksy,
    const float* __restrict__ kcn, float* __restrict__ out)
{
    const int p = blockIdx.x / NSL, s = blockIdx.x % NSL;
    const int tid = threadIdx.x;
    const int M = M_g[p];
    const unsigned int* cm = cmb_g + p * CAP;
    const int base = p * NPTS;
    float* ok = out + (size_t)2 * NP * NPTS + base;

    const int chunk = (M + NSL - 1) / NSL;
    const int e0 = s * chunk, e1 = min(M, e0 + chunk);

    for (int e = e0 + tid; e < e1; e += WTHR) {
        unsigned int w = cm[e];
        if ((w & 3u) != ST_A) continue;
        int n = (int)(w >> 2);
        int r = KRANK_G(p, e);
        float c = kcn[p * CAP + r];
        out[2 * (base + n)]     = ksx[p * CAP + r] / c;   // c >= 1 (self-assign)
        out[2 * (base + n) + 1] = ksy[p * CAP + r] / c;
        ok[n] = 1.0f;
    }
}

// ---------------------------------------------------------------------------
extern "C" void kernel_launch(void* const* d_in, const int* in_sizes, int n_in,
                              void* d_out, int out_size, void* d_ws, size_t ws_size,
                              hipStream_t stream) {
    const float* seg   = (const float*)d_in[0];   // [B,C,H,W] f32
    const float* lidar = (const float*)d_in[1];   // [B,2,H,W] f32
    float* out = (float*)d_out;
    float* wsf = (float*)d_ws;

    float* xs = wsf;                                          // 16384
    float* ys = wsf + 16384;                                  // 16384
    unsigned int* ns = (unsigned int*)(wsf + 32768);          // 16384
    unsigned int* counts = (unsigned int*)(wsf + 49152);      // 384
    float2* sps_g = (float2*)(wsf + 49536);                   // 6*4096 f2 -> 98688
    unsigned int* cmb_g = (unsigned int*)(wsf + 98688);       // 24576    -> 123264
    unsigned int* cellpack_g = (unsigned int*)(wsf + 123264); // 98304    -> 221568
    float* bbox_g = wsf + 221568;                             // 24
    int* M_g = (int*)(wsf + 221592);                          // 6 (+2 pad)
    unsigned long long* ballots_g = (unsigned long long*)(wsf + 221600); // 384 u64
    unsigned int* base_g = (unsigned int*)(wsf + 222368);     // 384
    float* ksx = wsf + 222752;                                // 24576
    float* ksy = wsf + 247328;                                // 24576
    float* kcn = wsf + 271904;                                // 24576

    k_front <<<KBLK, KTHR, 0, stream>>>(seg, lidar, xs, ys, ns, counts, ksx, out);
    k_mid   <<<NP, 1024, 0, stream>>>(xs, ys, ns, counts, sps_g, cmb_g, cellpack_g,
                                      bbox_g, M_g, ballots_g, base_g);
    k_assign<<<WBLK, WTHR, 0, stream>>>(sps_g, cmb_g, cellpack_g, bbox_g, M_g,
                                        ballots_g, base_g, ksx, ksy, kcn);
    k_out   <<<WBLK, WTHR, 0, stream>>>(cmb_g, M_g, ballots_g, base_g, ksx, ksy, kcn, out);
}